// Round 1
// baseline (542.164 us; speedup 1.0000x reference)
//
#include <hip/hip_runtime.h>
#include <math.h>

#define BB   64
#define PTS  4096
#define NTOT (BB * PTS)
#define OBS  128
#define ACT  5
#define HID  256
#define LAT  64
#define CTX  128
#define LOG2PIE 2.8378770664093453f

// output offsets (floats): h, z, context, priority, priority_norm, uncertainty
#define OFF_H   0
#define OFF_Z   (BB * HID)              // 16384
#define OFF_CTX (OFF_Z + BB * LAT)      // 20480
#define OFF_PRI (OFF_CTX + BB * CTX)    // 28672
#define OFF_PN  (OFF_PRI + NTOT)        // 290816
#define OFF_UNC (OFF_PN + NTOT)         // 552960

#define CHUNKS 32                       // partial-sum chunks per segment
#define RPC    (PTS / CHUNKS)           // 128 rows per chunk

__device__ __forceinline__ float wsum(float v) {
    #pragma unroll
    for (int off = 32; off > 0; off >>= 1) v += __shfl_xor(v, off, 64);
    return v;
}
__device__ __forceinline__ float wmax(float v) {
    #pragma unroll
    for (int off = 32; off > 0; off >>= 1) v = fmaxf(v, __shfl_xor(v, off, 64));
    return v;
}
__device__ __forceinline__ float sigmoidf_(float x) { return 1.f / (1.f + expf(-x)); }

// 4-row lane-strided dot over K (K multiple of 64), x in LDS, row-major W.
template <int K>
__device__ __forceinline__ void rows4_dot(const float* __restrict__ W, int r0,
                                          const float* __restrict__ x,
                                          float& a0, float& a1, float& a2, float& a3) {
    const int lane = threadIdx.x & 63;
    const float* w0 = W + (size_t)r0 * K;
    const float* w1 = w0 + K;
    const float* w2 = w0 + 2 * K;
    const float* w3 = w0 + 3 * K;
    float xs = x[lane];
    a0 = w0[lane] * xs; a1 = w1[lane] * xs; a2 = w2[lane] * xs; a3 = w3[lane] * xs;
    #pragma unroll
    for (int s = 1; s < K / 64; ++s) {
        xs = x[lane + 64 * s];
        a0 = fmaf(w0[lane + 64 * s], xs, a0);
        a1 = fmaf(w1[lane + 64 * s], xs, a1);
        a2 = fmaf(w2[lane + 64 * s], xs, a2);
        a3 = fmaf(w3[lane + 64 * s], xs, a3);
    }
    a0 = wsum(a0); a1 = wsum(a1); a2 = wsum(a2); a3 = wsum(a3);
}

// ============ phase1: blocks [0,2048) = obs segment partials; [2048,6144) = GRU ============
// NOTE (R6 lesson): no grid.sync — cooperative grid barrier costs ~100 µs on MI355X.
// Block 0 additionally zeroes the attention accumulator + per-segment counters
// (visible to kernel 2 via the dispatch boundary).
__global__ __launch_bounds__(256) void phase1_kernel(
        const float* __restrict__ obs, float* __restrict__ part,
        const float* __restrict__ action, const float* __restrict__ coh_scalar,
        const float* __restrict__ h_prev, const float* __restrict__ z_prev,
        const float* __restrict__ W_ih, const float* __restrict__ b_ih,
        const float* __restrict__ W_hh, const float* __restrict__ b_hh,
        float* __restrict__ att_acc, int* __restrict__ cnt,
        float* __restrict__ out) {
    __shared__ float4 lds[256];
    int t = threadIdx.x;
    if (blockIdx.x < BB * CHUNKS) {
        if (blockIdx.x == 0) {
            #pragma unroll
            for (int i = 0; i < (BB * OBS) / 256; ++i) att_acc[t + 256 * i] = 0.f;
            if (t < BB) cnt[t] = 0;
        }
        // ---- obs segment partial sums ----
        int blk = blockIdx.x;
        int b = blk >> 5, chunk = blk & 31;
        int c4 = t & 31, rg = t >> 5;
        const float4* obs4 = (const float4*)obs;
        size_t row0 = (size_t)b * PTS + (size_t)chunk * RPC;
        float4 acc = make_float4(0.f, 0.f, 0.f, 0.f);
        #pragma unroll
        for (int i = 0; i < RPC / 8; ++i) {
            float4 v = obs4[(row0 + rg + 8 * i) * (OBS / 4) + c4];
            acc.x += v.x; acc.y += v.y; acc.z += v.z; acc.w += v.w;
        }
        lds[t] = acc;
        __syncthreads();
        if (t < 32) {
            float4 s = lds[t];
            #pragma unroll
            for (int k = 1; k < 8; ++k) {
                float4 v = lds[t + 32 * k];
                s.x += v.x; s.y += v.y; s.z += v.z; s.w += v.w;
            }
            ((float4*)part)[(size_t)blk * 32 + t] = s;
        }
    } else {
        // ---- GRU: one wave per (b, j) ----
        int wid = (blockIdx.x - BB * CHUNKS) * 4 + (t >> 6);
        int lane = t & 63;
        int b = wid >> 8, j = wid & 255;

        float x0 = z_prev[b * LAT + lane];
        float x1 = 0.f;
        if (lane < ACT) x1 = action[b * ACT + lane];
        else if (lane == ACT) x1 = coh_scalar[b];
        float hp0 = h_prev[b * HID + lane];
        float hp1 = h_prev[b * HID + lane + 64];
        float hp2 = h_prev[b * HID + lane + 128];
        float hp3 = h_prev[b * HID + lane + 192];

        const float* wir = W_ih + (size_t)j * 70;
        const float* wiz = W_ih + (size_t)(HID + j) * 70;
        const float* win = W_ih + (size_t)(2 * HID + j) * 70;
        const float* whr = W_hh + (size_t)j * HID;
        const float* whz = W_hh + (size_t)(HID + j) * HID;
        const float* whn = W_hh + (size_t)(2 * HID + j) * HID;

        float sr = wir[lane] * x0;
        float sz = wiz[lane] * x0;
        float sn = win[lane] * x0;
        if (lane < 6) {
            sr = fmaf(wir[lane + 64], x1, sr);
            sz = fmaf(wiz[lane + 64], x1, sz);
            sn = fmaf(win[lane + 64], x1, sn);
        }
        sr = fmaf(whr[lane], hp0, sr); sr = fmaf(whr[lane + 64], hp1, sr);
        sr = fmaf(whr[lane + 128], hp2, sr); sr = fmaf(whr[lane + 192], hp3, sr);
        sz = fmaf(whz[lane], hp0, sz); sz = fmaf(whz[lane + 64], hp1, sz);
        sz = fmaf(whz[lane + 128], hp2, sz); sz = fmaf(whz[lane + 192], hp3, sz);
        float sh = whn[lane] * hp0;
        sh = fmaf(whn[lane + 64], hp1, sh);
        sh = fmaf(whn[lane + 128], hp2, sh);
        sh = fmaf(whn[lane + 192], hp3, sh);

        sr = wsum(sr); sz = wsum(sz); sn = wsum(sn); sh = wsum(sh);
        if (lane == 0) {
            float r = sigmoidf_(sr + b_ih[j] + b_hh[j]);
            float u = sigmoidf_(sz + b_ih[HID + j] + b_hh[HID + j]);
            float n = tanhf(sn + b_ih[2 * HID + j] + r * (sh + b_hh[2 * HID + j]));
            float h = (1.f - u) * n + u * h_prev[b * HID + j];
            out[OFF_H + b * HID + j] = h;
        }
    }
}

// ============ fused tail: 2048 blocks x 256 (one per (b,chunk)) ============
// Each block redundantly recomputes segment-local quantities (agg, posterior
// logvar -> u, softmax max/denom: all deterministic and bitwise-identical
// across the 32 chunk-blocks of a segment), writes its own chunk's PRI/PN,
// accumulates its attention-weighted obs partial via device-scope atomicAdd,
// then the LAST-arriving block of each segment (threadfence + atomic counter,
// no spinning -> no residency assumption) runs the head MLP.
__global__ __launch_bounds__(256) void fused_tail_kernel(
        const float* __restrict__ obs, const float* __restrict__ part,
        const float* __restrict__ coh_spatial,
        const float* __restrict__ W_post, const float* __restrict__ b_post,
        const float* __restrict__ W_ae1, const float* __restrict__ b_ae1,
        const float* __restrict__ W_ae2, const float* __restrict__ b_ae2,
        const float* __restrict__ W_c1,  const float* __restrict__ b_c1,
        const float* __restrict__ W_c2,  const float* __restrict__ b_c2,
        float* __restrict__ att_acc, int* __restrict__ cnt,
        float* __restrict__ out) {
    const int blk = blockIdx.x, b = blk >> 5, chunk = blk & 31;
    const int t = threadIdx.x, w = t >> 6, lane = t & 63;

    __shared__ float hsagg[384];     // [h(256) | agg(128)] = posterior input
    __shared__ float ss[4096];       // stage-A scratch, then softmax s/e values
    __shared__ float lvs[64];
    __shared__ float red[4];
    __shared__ float4 red4[256];
    __shared__ float uS;
    __shared__ int lastS;
    __shared__ float attS[128];
    __shared__ float ctxin[448];     // [h(256) | z(64) | obs_enc(128)]
    __shared__ float h1[256];
    __shared__ float c1v[512];

    // ---- A: load h, reduce part -> agg ----
    hsagg[t] = out[OFF_H + b * HID + t];
    {
        const int c = t & 127, half = t >> 7;
        const float* p = part + (size_t)b * (CHUNKS * OBS) + (size_t)half * 16 * OBS + c;
        float s = 0.f;
        #pragma unroll
        for (int k = 0; k < 16; ++k) s += p[k * OBS];
        ss[t] = s;
    }
    __syncthreads();
    if (t < 128) hsagg[256 + t] = (ss[t] + ss[t + 128]) * (1.0f / PTS);
    __syncthreads();

    // ---- B: posterior logvar rows (64..127) -> u; chunk 0 also writes z ----
    {
        float a0, a1, a2, a3;
        #pragma unroll
        for (int g = 0; g < 4; ++g) {
            int r0 = 64 + w * 16 + g * 4;
            rows4_dot<384>(W_post, r0, hsagg, a0, a1, a2, a3);
            if (lane == 0) {
                lvs[r0 - 64] = a0 + b_post[r0];
                lvs[r0 - 63] = a1 + b_post[r0 + 1];
                lvs[r0 - 62] = a2 + b_post[r0 + 2];
                lvs[r0 - 61] = a3 + b_post[r0 + 3];
            }
        }
        if (chunk == 0) {
            #pragma unroll
            for (int g = 0; g < 4; ++g) {
                int r0 = w * 16 + g * 4;
                rows4_dot<384>(W_post, r0, hsagg, a0, a1, a2, a3);
                if (lane == 0) {
                    float* dst = out + OFF_Z + b * LAT + r0;
                    dst[0] = a0 + b_post[r0];     dst[1] = a1 + b_post[r0 + 1];
                    dst[2] = a2 + b_post[r0 + 2]; dst[3] = a3 + b_post[r0 + 3];
                }
            }
        }
    }
    __syncthreads();
    if (w == 0) {
        float v = wsum(lvs[lane]);
        if (lane == 0) {
            float uu = 0.5f * v + 32.0f * LOG2PIE;
            uS = uu;
            if (chunk == 0) out[OFF_UNC + b] = uu;
        }
    }
    __syncthreads();
    const float u = uS;

    // ---- C: per-segment softmax stats (redundant, deterministic); write own chunk PRI/PN ----
    const int base = b * PTS;
    float lmax = -INFINITY;
    #pragma unroll
    for (int k = 0; k < 16; ++k) {
        int i = t + 256 * k;
        float s = coh_spatial[base + i] * u;
        ss[i] = s;
        lmax = fmaxf(lmax, s);
    }
    lmax = wmax(lmax);
    if (lane == 0) red[w] = lmax;
    __syncthreads();
    const float m = fmaxf(fmaxf(red[0], red[1]), fmaxf(red[2], red[3]));
    if (t < 128) out[OFF_PRI + base + chunk * RPC + t] = ss[chunk * RPC + t];  // TEMP = 1.0
    __syncthreads();
    float lsum = 0.f;
    #pragma unroll
    for (int k = 0; k < 16; ++k) {
        int i = t + 256 * k;
        float e = expf(ss[i] - m);
        ss[i] = e;
        lsum += e;
    }
    lsum = wsum(lsum);
    if (lane == 0) red[w] = lsum;
    __syncthreads();
    const float inv = 1.0f / fmaxf(red[0] + red[1] + red[2] + red[3], 1e-12f);
    if (t < 128) out[OFF_PN + base + chunk * RPC + t] = ss[chunk * RPC + t] * inv;

    // ---- D: attention-weighted obs partial for this chunk -> atomic accumulate ----
    {
        const int c4 = t & 31, rg = t >> 5;
        const float4* obs4 = (const float4*)obs;
        const size_t row0 = (size_t)b * PTS + (size_t)chunk * RPC;
        float4 acc = make_float4(0.f, 0.f, 0.f, 0.f);
        #pragma unroll
        for (int i2 = 0; i2 < RPC / 8; ++i2) {
            int r = rg + 8 * i2;
            float wgt = ss[chunk * RPC + r] * inv;
            float4 v = obs4[(row0 + r) * (OBS / 4) + c4];
            acc.x = fmaf(v.x, wgt, acc.x);
            acc.y = fmaf(v.y, wgt, acc.y);
            acc.z = fmaf(v.z, wgt, acc.z);
            acc.w = fmaf(v.w, wgt, acc.w);
        }
        red4[t] = acc;
        __syncthreads();
        if (t < 32) {
            float4 s4 = red4[t];
            #pragma unroll
            for (int k = 1; k < 8; ++k) {
                float4 v = red4[t + 32 * k];
                s4.x += v.x; s4.y += v.y; s4.z += v.z; s4.w += v.w;
            }
            float* dst = att_acc + b * OBS + 4 * t;
            atomicAdd(dst + 0, s4.x); atomicAdd(dst + 1, s4.y);
            atomicAdd(dst + 2, s4.z); atomicAdd(dst + 3, s4.w);
        }
    }
    __syncthreads();   // all atomics issued & drained (barrier implies vmcnt(0))
    if (t == 0) {
        __threadfence();
        int old = atomicAdd(&cnt[b], 1);
        lastS = (old == CHUNKS - 1) ? 1 : 0;
    }
    __syncthreads();
    if (!lastS) return;
    __threadfence();   // acquire side for all remaining threads

    // ---- E: head (last-arriving block of segment b only) ----
    if (t < 128)
        attS[t] = __hip_atomic_load(&att_acc[b * OBS + t], __ATOMIC_ACQUIRE,
                                    __HIP_MEMORY_SCOPE_AGENT);
    ctxin[t] = hsagg[t];                 // h
    {
        float a0, a1, a2, a3;            // z = mu_q (recompute; hsagg still live)
        #pragma unroll
        for (int g = 0; g < 4; ++g) {
            int r0 = w * 16 + g * 4;
            rows4_dot<384>(W_post, r0, hsagg, a0, a1, a2, a3);
            if (lane == 0) {
                ctxin[256 + r0]     = a0 + b_post[r0];
                ctxin[256 + r0 + 1] = a1 + b_post[r0 + 1];
                ctxin[256 + r0 + 2] = a2 + b_post[r0 + 2];
                ctxin[256 + r0 + 3] = a3 + b_post[r0 + 3];
            }
        }
    }
    __syncthreads();
    {   // ae1: 256 rows, k=128, relu
        float a0, a1, a2, a3;
        for (int g = 0; g < 16; ++g) {
            int r0 = w * 64 + g * 4;
            rows4_dot<128>(W_ae1, r0, attS, a0, a1, a2, a3);
            if (lane == 0) {
                h1[r0]     = fmaxf(a0 + b_ae1[r0],     0.f);
                h1[r0 + 1] = fmaxf(a1 + b_ae1[r0 + 1], 0.f);
                h1[r0 + 2] = fmaxf(a2 + b_ae1[r0 + 2], 0.f);
                h1[r0 + 3] = fmaxf(a3 + b_ae1[r0 + 3], 0.f);
            }
        }
    }
    __syncthreads();
    {   // ae2: 128 rows, k=256 -> obs_enc
        float a0, a1, a2, a3;
        for (int g = 0; g < 8; ++g) {
            int r0 = w * 32 + g * 4;
            rows4_dot<256>(W_ae2, r0, h1, a0, a1, a2, a3);
            if (lane == 0) {
                ctxin[320 + r0]     = a0 + b_ae2[r0];
                ctxin[320 + r0 + 1] = a1 + b_ae2[r0 + 1];
                ctxin[320 + r0 + 2] = a2 + b_ae2[r0 + 2];
                ctxin[320 + r0 + 3] = a3 + b_ae2[r0 + 3];
            }
        }
    }
    __syncthreads();
    {   // c1: 512 rows, k=448, relu
        float a0, a1, a2, a3;
        for (int g = 0; g < 32; ++g) {
            int r0 = w * 128 + g * 4;
            rows4_dot<448>(W_c1, r0, ctxin, a0, a1, a2, a3);
            if (lane == 0) {
                c1v[r0]     = fmaxf(a0 + b_c1[r0],     0.f);
                c1v[r0 + 1] = fmaxf(a1 + b_c1[r0 + 1], 0.f);
                c1v[r0 + 2] = fmaxf(a2 + b_c1[r0 + 2], 0.f);
                c1v[r0 + 3] = fmaxf(a3 + b_c1[r0 + 3], 0.f);
            }
        }
    }
    __syncthreads();
    {   // c2: 128 rows, k=512 -> context
        float a0, a1, a2, a3;
        for (int g = 0; g < 8; ++g) {
            int r0 = w * 32 + g * 4;
            rows4_dot<512>(W_c2, r0, c1v, a0, a1, a2, a3);
            if (lane == 0) {
                float* dst = out + OFF_CTX + b * CTX + r0;
                dst[0] = a0 + b_c2[r0];     dst[1] = a1 + b_c2[r0 + 1];
                dst[2] = a2 + b_c2[r0 + 2]; dst[3] = a3 + b_c2[r0 + 3];
            }
        }
    }
}

extern "C" void kernel_launch(void* const* d_in, const int* in_sizes, int n_in,
                              void* d_out, int out_size, void* d_ws, size_t ws_size,
                              hipStream_t stream) {
    const float* obs         = (const float*)d_in[0];
    const float* action      = (const float*)d_in[1];
    const float* coh_scalar  = (const float*)d_in[2];
    const float* coh_spatial = (const float*)d_in[3];
    const float* h_prev      = (const float*)d_in[4];
    const float* z_prev      = (const float*)d_in[5];
    // d_in[6] = batch: structurally i >> 12 — not read.
    const float* W_ih   = (const float*)d_in[7];
    const float* b_ih   = (const float*)d_in[8];
    const float* W_hh   = (const float*)d_in[9];
    const float* b_hh   = (const float*)d_in[10];
    // d_in[11]/d_in[12] = W_prior/b_prior: dead.
    const float* W_post = (const float*)d_in[13];
    const float* b_post = (const float*)d_in[14];
    const float* W_ae1  = (const float*)d_in[15];
    const float* b_ae1  = (const float*)d_in[16];
    const float* W_ae2  = (const float*)d_in[17];
    const float* b_ae2  = (const float*)d_in[18];
    const float* W_c1   = (const float*)d_in[19];
    const float* b_c1   = (const float*)d_in[20];
    const float* W_c2   = (const float*)d_in[21];
    const float* b_c2   = (const float*)d_in[22];

    float* out      = (float*)d_out;
    float* part     = (float*)d_ws;                    // 64*32*128 floats
    float* att_acc  = part + BB * CHUNKS * OBS;        // 64*128 floats
    int*   cnt      = (int*)(att_acc + BB * OBS);      // 64 ints

    phase1_kernel<<<BB * CHUNKS + BB * HID / 4, 256, 0, stream>>>(
        obs, part, action, coh_scalar, h_prev, z_prev, W_ih, b_ih, W_hh, b_hh,
        att_acc, cnt, out);
    fused_tail_kernel<<<BB * CHUNKS, 256, 0, stream>>>(
        obs, part, coh_spatial, W_post, b_post, W_ae1, b_ae1, W_ae2, b_ae2,
        W_c1, b_c1, W_c2, b_c2, att_acc, cnt, out);
}